// Round 1
// 1361.481 us; speedup vs baseline: 1.8906x; 1.8906x over previous
//
#include <hip/hip_runtime.h>

#define NN 10000
#define NE 160000
#define INV_SQRT3 0.57735026918962576f
#define INV_SQRT2 0.70710678118654752f

__device__ __forceinline__ float silu_f(float x) { return x / (1.0f + __expf(-x)); }

// ---------------------------------------------------------------------------
// Kernel 1: node-wise pre-projection + gate (unchanged — tiny vs edge kernel).
// ---------------------------------------------------------------------------
__global__ __launch_bounds__(64) void node_pre_kernel(
    const float* __restrict__ x,
    const float* __restrict__ W_pre_s, const float* __restrict__ b_pre_s,
    const float* __restrict__ W_pre_v,
    const float* __restrict__ gw_pre, const float* __restrict__ gb_pre,
    float* __restrict__ s_p, float* __restrict__ v_p)
{
    int n = blockIdx.x;
    int t = threadIdx.x;  // 0..63
    __shared__ float xs[64];
    __shared__ float xv[192];  // xv[u*3+c]
    const float4* row = (const float4*)(x + n * 256);
    {
        float4 v = row[t];
        int idx = t * 4;
        float tmp[4] = {v.x, v.y, v.z, v.w};
#pragma unroll
        for (int i = 0; i < 4; i++) {
            int id = idx + i;
            if (id < 64) xs[id] = tmp[i];
            else         xv[id - 64] = tmp[i];
        }
    }
    __syncthreads();

    float acc_s = b_pre_s[t];
    float a0 = 0.f, a1 = 0.f, a2 = 0.f;
    for (int u = 0; u < 64; u++) {
        float xsu = xs[u];
        acc_s += xsu * W_pre_s[u * 64 + t];
        float wv = W_pre_v[u * 64 + t];
        a0 += xv[u * 3 + 0] * wv;
        a1 += xv[u * 3 + 1] * wv;
        a2 += xv[u * 3 + 2] * wv;
    }
    float nrm = sqrtf(a0 * a0 + a1 * a1 + a2 * a2 + 1e-12f);
    float g = silu_f(nrm * gw_pre[t] + gb_pre[t]);
    s_p[n * 64 + t] = silu_f(acc_s);
    float* vp = v_p + (n * 64 + t) * 3;
    vp[0] = a0 * g;
    vp[1] = a1 * g;
    vp[2] = a2 * g;
}

// ---------------------------------------------------------------------------
// Kernel 2: fused edge pipeline, register-blocked over EPW=8 edges per wave.
// Lane u owns channel u. Edge-side operands live transposed in LDS ([k][E]),
// read at wave-uniform addresses (broadcast, conflict-free). Each weight load
// feeds 8 (GEMM stages) / 4 (post stages) FMAs -> L2 weight traffic /8.
// ---------------------------------------------------------------------------
#define FMA8(ACC, WV, A4, B4) \
    ACC[0] += (WV) * (A4).x; ACC[1] += (WV) * (A4).y; \
    ACC[2] += (WV) * (A4).z; ACC[3] += (WV) * (A4).w; \
    ACC[4] += (WV) * (B4).x; ACC[5] += (WV) * (B4).y; \
    ACC[6] += (WV) * (B4).z; ACC[7] += (WV) * (B4).w;

__global__ __launch_bounds__(256, 3) void edge_kernel(
    const float* __restrict__ x,
    const float* __restrict__ edge_attr,
    const float* __restrict__ fij_in,
    const float* __restrict__ Ws1, const float* __restrict__ bs1,
    const float* __restrict__ Ws2, const float* __restrict__ bs2,
    const float* __restrict__ Wr1, const float* __restrict__ br1,
    const float* __restrict__ Wr2, const float* __restrict__ br2,
    const float* __restrict__ gw_post, const float* __restrict__ gb_post,
    const float* __restrict__ W_post_s, const float* __restrict__ W_post_v,
    const int* __restrict__ ei,
    const float* __restrict__ s_p, const float* __restrict__ v_p,
    float* __restrict__ out)
{
    // Per-wave LDS region (2816 floats = 11264 B), overlaid across stages:
    //   stages 1-5 : s0T [192][8] at 0..1535 ; hbT [128][8] at 1536..2559
    //               (eaT [20][8] overlays s0T after s0T is dead)
    //   stages 6-7 : osbT [128][4] at 0..511 ; ovT [192][12] at 512..2815
    //               obB [4][256] at 0..1023 (after post-GEMM reads)
    __shared__ __align__(16) float smem[4][2816];

    int tid = threadIdx.x;
    int w = tid >> 6;   // wave in block
    int u = tid & 63;   // lane = channel
    float* S   = smem[w];
    float* s0T = S;             // [192][8]
    float* hbT = S + 1536;      // [128][8]
    float* eaT = S;             // [20][8]  (overlay)
    float* osbT = S;            // [128][4] (overlay)
    float* ovT  = S + 512;      // [192][12] (overlay)
    float* obB  = S;            // [4][256] (overlay)

    int e8 = blockIdx.x * 32 + w * 8;   // this wave's 8 edges

    // ---- gather: build s0T[k][e] = [xs_i | xs_j | dot_v] ----
#pragma unroll 2
    for (int e = 0; e < 8; e++) {
        int eg = e8 + e;
        int sp = ei[eg];
        int dp = ei[NE + eg];
        const float* xr = x + sp * 256;
        const float* yr = x + dp * 256;
        float xsi = xr[u];
        float xsj = yr[u];
        float a0 = xr[64 + 3 * u], a1 = xr[65 + 3 * u], a2 = xr[66 + 3 * u];
        float b0 = yr[64 + 3 * u], b1 = yr[65 + 3 * u], b2 = yr[66 + 3 * u];
        s0T[u * 8 + e]         = xsi;
        s0T[(64 + u) * 8 + e]  = xsj;
        s0T[(128 + u) * 8 + e] = a0 * b0 + a1 * b1 + a2 * b2;
    }
    __syncthreads();

    // ---- h1 = silu(s0 @ Ws1 + bs1); lane u -> channels u, 64+u; 8 edges ----
    float acc0[8], acc1[8];
    {
        float b0v = bs1[u], b1v = bs1[64 + u];
#pragma unroll
        for (int e = 0; e < 8; e++) { acc0[e] = b0v; acc1[e] = b1v; }
    }
#pragma unroll 4
    for (int k = 0; k < 192; k++) {
        float4 sA = *(const float4*)&s0T[k * 8];
        float4 sB = *(const float4*)&s0T[k * 8 + 4];
        float w0 = Ws1[k * 128 + u];
        float w1 = Ws1[k * 128 + 64 + u];
        FMA8(acc0, w0, sA, sB);
        FMA8(acc1, w1, sA, sB);
    }
#pragma unroll
    for (int e = 0; e < 8; e++) {
        hbT[u * 8 + e]        = silu_f(acc0[e]);
        hbT[(64 + u) * 8 + e] = silu_f(acc1[e]);
    }
    __syncthreads();

    // ---- tp_a = h1 @ Ws2 + bs2 ; lane u -> channels m*64+u, 8 edges ----
    float tpa[5][8];
#pragma unroll
    for (int m = 0; m < 5; m++) {
        float bb = bs2[m * 64 + u];
#pragma unroll
        for (int e = 0; e < 8; e++) tpa[m][e] = bb;
    }
#pragma unroll 2
    for (int k = 0; k < 128; k++) {
        float4 hA = *(const float4*)&hbT[k * 8];
        float4 hB = *(const float4*)&hbT[k * 8 + 4];
#pragma unroll
        for (int m = 0; m < 5; m++) {
            float wv = Ws2[k * 320 + m * 64 + u];
            float* tm = tpa[m];
            FMA8(tm, wv, hA, hB);
        }
    }
    __syncthreads();

    // ---- eaT[k][e] = edge_attr (overlays dead s0T) ----
    if (u < 20) {
#pragma unroll
        for (int e = 0; e < 8; e++) eaT[u * 8 + e] = edge_attr[(e8 + e) * 20 + u];
    }
    __syncthreads();

    // ---- hr = silu(ea @ Wr1 + br1) ----
    {
        float c0v = br1[u], c1v = br1[64 + u];
#pragma unroll
        for (int e = 0; e < 8; e++) { acc0[e] = c0v; acc1[e] = c1v; }
    }
#pragma unroll
    for (int k = 0; k < 20; k++) {
        float4 aA = *(const float4*)&eaT[k * 8];
        float4 aB = *(const float4*)&eaT[k * 8 + 4];
        float w0 = Wr1[k * 128 + u];
        float w1 = Wr1[k * 128 + 64 + u];
        FMA8(acc0, w0, aA, aB);
        FMA8(acc1, w1, aA, aB);
    }
    __syncthreads();
#pragma unroll
    for (int e = 0; e < 8; e++) {
        hbT[u * 8 + e]        = silu_f(acc0[e]);
        hbT[(64 + u) * 8 + e] = silu_f(acc1[e]);
    }
    __syncthreads();

    // ---- tp_w = (hr @ Wr2 + br2) * tp_a ----
    float wgt[5][8];
#pragma unroll
    for (int m = 0; m < 5; m++) {
        float bb = br2[m * 64 + u];
#pragma unroll
        for (int e = 0; e < 8; e++) wgt[m][e] = bb;
    }
#pragma unroll 2
    for (int k = 0; k < 128; k++) {
        float4 hA = *(const float4*)&hbT[k * 8];
        float4 hB = *(const float4*)&hbT[k * 8 + 4];
#pragma unroll
        for (int m = 0; m < 5; m++) {
            float wv = Wr2[k * 320 + m * 64 + u];
            float* wm = wgt[m];
            FMA8(wm, wv, hA, hB);
        }
    }
#pragma unroll
    for (int m = 0; m < 5; m++)
#pragma unroll
        for (int e = 0; e < 8; e++) wgt[m][e] *= tpa[m][e];
    __syncthreads();   // s0T/hbT dead; stage-6 overlays begin

    // ---- tensor product + post gate + post GEMMs, 2 passes of 4 edges ----
#pragma unroll
    for (int p = 0; p < 2; p++) {
#pragma unroll
        for (int e = 0; e < 4; e++) {
            int el = p * 4 + e;
            int eg = e8 + el;
            int sp = ei[eg], dp = ei[NE + eg];
            float si = s_p[sp * 64 + u];
            float sj = s_p[dp * 64 + u];
            const float* vip = v_p + (sp * 64 + u) * 3;
            const float* vjp = v_p + (dp * 64 + u) * 3;
            float vi0 = vip[0], vi1 = vip[1], vi2 = vip[2];
            float vj0 = vjp[0], vj1 = vjp[1], vj2 = vjp[2];
            float dv = vi0 * vj0 + vi1 * vj1 + vi2 * vj2;

            float w1 = wgt[0][el], w2 = wgt[1][el], w3 = wgt[2][el];
            float w4 = wgt[3][el], w5 = wgt[4][el];

            float os1 = silu_f(w1 * si * sj);
            float os2 = silu_f(w4 * dv * INV_SQRT3);

            float r00 = w2 * si * vj0, r01 = w2 * si * vj1, r02 = w2 * si * vj2;
            float r10 = w3 * sj * vi0, r11 = w3 * sj * vi1, r12 = w3 * sj * vi2;
            float cx = vi1 * vj2 - vi2 * vj1;
            float cy = vi2 * vj0 - vi0 * vj2;
            float cz = vi0 * vj1 - vi1 * vj0;
            float r20 = w5 * cx * INV_SQRT2;
            float r21 = w5 * cy * INV_SQRT2;
            float r22 = w5 * cz * INV_SQRT2;

            float n0 = sqrtf(r00 * r00 + r01 * r01 + r02 * r02 + 1e-12f);
            float g0 = silu_f(n0 * gw_post[u] + gb_post[u]);
            float n1 = sqrtf(r10 * r10 + r11 * r11 + r12 * r12 + 1e-12f);
            float g1 = silu_f(n1 * gw_post[64 + u] + gb_post[64 + u]);
            float n2 = sqrtf(r20 * r20 + r21 * r21 + r22 * r22 + 1e-12f);
            float g2 = silu_f(n2 * gw_post[128 + u] + gb_post[128 + u]);

            osbT[u * 4 + e]        = os1;
            osbT[(64 + u) * 4 + e] = os2;
            ovT[u * 12 + 0 * 4 + e] = r00 * g0;
            ovT[u * 12 + 1 * 4 + e] = r01 * g0;
            ovT[u * 12 + 2 * 4 + e] = r02 * g0;
            ovT[(64 + u) * 12 + 0 * 4 + e] = r10 * g1;
            ovT[(64 + u) * 12 + 1 * 4 + e] = r11 * g1;
            ovT[(64 + u) * 12 + 2 * 4 + e] = r12 * g1;
            ovT[(128 + u) * 12 + 0 * 4 + e] = r20 * g2;
            ovT[(128 + u) * 12 + 1 * 4 + e] = r21 * g2;
            ovT[(128 + u) * 12 + 2 * 4 + e] = r22 * g2;
        }
        __syncthreads();

        // fij_s = out_s @ W_post_s  (4 edges per weight load)
        float fs[4] = {0.f, 0.f, 0.f, 0.f};
#pragma unroll 2
        for (int k = 0; k < 128; k++) {
            float4 ov = *(const float4*)&osbT[k * 4];
            float wv = W_post_s[k * 64 + u];
            fs[0] += ov.x * wv; fs[1] += ov.y * wv;
            fs[2] += ov.z * wv; fs[3] += ov.w * wv;
        }
        // fij_v = out_v @ W_post_v
        float fv[4][3];
#pragma unroll
        for (int e = 0; e < 4; e++) { fv[e][0] = 0.f; fv[e][1] = 0.f; fv[e][2] = 0.f; }
#pragma unroll 2
        for (int k = 0; k < 192; k++) {
            float4 q0 = *(const float4*)&ovT[k * 12];
            float4 q1 = *(const float4*)&ovT[k * 12 + 4];
            float4 q2 = *(const float4*)&ovT[k * 12 + 8];
            float wv = W_post_v[k * 64 + u];
            fv[0][0] += q0.x * wv; fv[1][0] += q0.y * wv; fv[2][0] += q0.z * wv; fv[3][0] += q0.w * wv;
            fv[0][1] += q1.x * wv; fv[1][1] += q1.y * wv; fv[2][1] += q1.z * wv; fv[3][1] += q1.w * wv;
            fv[0][2] += q2.x * wv; fv[1][2] += q2.y * wv; fv[2][2] += q2.z * wv; fv[3][2] += q2.w * wv;
        }
        __syncthreads();

        // stage outputs for coalesced write (overlays osbT/ovT head)
#pragma unroll
        for (int e = 0; e < 4; e++) {
            obB[e * 256 + u] = fs[e];
            obB[e * 256 + 64 + 3 * u + 0] = fv[e][0];
            obB[e * 256 + 64 + 3 * u + 1] = fv[e][1];
            obB[e * 256 + 64 + 3 * u + 2] = fv[e][2];
        }
        __syncthreads();

#pragma unroll
        for (int e = 0; e < 4; e++) {
            int eg = e8 + p * 4 + e;
            float4 fin = ((const float4*)fij_in)[eg * 64 + u];
            float4 o4 = *(const float4*)&obB[e * 256 + 4 * u];
            o4.x += fin.x; o4.y += fin.y; o4.z += fin.z; o4.w += fin.w;
            ((float4*)out)[eg * 64 + u] = o4;
        }
        __syncthreads();
    }
}

extern "C" void kernel_launch(void* const* d_in, const int* in_sizes, int n_in,
                              void* d_out, int out_size, void* d_ws, size_t ws_size,
                              hipStream_t stream)
{
    const float* x         = (const float*)d_in[0];
    const float* edge_attr = (const float*)d_in[1];
    const float* fij_in    = (const float*)d_in[2];
    const float* W_pre_s   = (const float*)d_in[3];
    const float* b_pre_s   = (const float*)d_in[4];
    const float* W_pre_v   = (const float*)d_in[5];
    const float* gw_pre    = (const float*)d_in[6];
    const float* gb_pre    = (const float*)d_in[7];
    const float* Ws1       = (const float*)d_in[8];
    const float* bs1       = (const float*)d_in[9];
    const float* Ws2       = (const float*)d_in[10];
    const float* bs2       = (const float*)d_in[11];
    const float* Wr1       = (const float*)d_in[12];
    const float* br1       = (const float*)d_in[13];
    const float* Wr2       = (const float*)d_in[14];
    const float* br2       = (const float*)d_in[15];
    const float* gw_post   = (const float*)d_in[16];
    const float* gb_post   = (const float*)d_in[17];
    const float* W_post_s  = (const float*)d_in[18];
    const float* W_post_v  = (const float*)d_in[19];
    const int*   ei        = (const int*)d_in[20];
    float* out = (float*)d_out;

    // workspace: s_p (N*64 fp32) + v_p (N*64*3 fp32) = 10.24 MB
    float* s_p = (float*)d_ws;
    float* v_p = s_p + NN * 64;

    node_pre_kernel<<<NN, 64, 0, stream>>>(x, W_pre_s, b_pre_s, W_pre_v,
                                           gw_pre, gb_pre, s_p, v_p);
    edge_kernel<<<NE / 32, 256, 0, stream>>>(x, edge_attr, fij_in,
                                             Ws1, bs1, Ws2, bs2,
                                             Wr1, br1, Wr2, br2,
                                             gw_post, gb_post, W_post_s, W_post_v,
                                             ei, s_p, v_p, out);
}

// Round 2
// 971.048 us; speedup vs baseline: 2.6507x; 1.4021x over previous
//
#include <hip/hip_runtime.h>

#define NN 10000
#define NE 160000
#define INV_SQRT3 0.57735026918962576f
#define INV_SQRT2 0.70710678118654752f

// bf16 weight workspace offsets (in ushorts)
#define O_WS1T 0        // [128][192]
#define O_WS2T 24576    // [320][128]
#define O_WR1T 65536    // [128][32]  (K padded 20->32 with zeros)
#define O_WR2T 69632    // [320][128]
#define O_WPS  110592   // [128][64]  (same layout as fp32, bf16)
#define O_WPV  118784   // [192][64]
#define W_TOTAL 131072

typedef __attribute__((ext_vector_type(8))) short bf16x8;
typedef __attribute__((ext_vector_type(4))) short bf16x4;
typedef __attribute__((ext_vector_type(4))) float f32x4;

__device__ __forceinline__ float silu_f(float x) { return x / (1.0f + __expf(-x)); }
__device__ __forceinline__ unsigned short f2bf(float f) {
    unsigned int uu = __float_as_uint(f);
    uu += 0x7fffu + ((uu >> 16) & 1u);     // RNE
    return (unsigned short)(uu >> 16);
}
__device__ __forceinline__ float bf2f(unsigned short v) {
    return __uint_as_float(((unsigned int)v) << 16);
}

// ---------------------------------------------------------------------------
// Kernel 0: one-time weight convert/transpose to bf16.
//   Ws1T[n][k]=Ws1[k][n], Ws2T[n][k]=Ws2[k][n], Wr1T[n][k] (K-padded),
//   Wr2T[n][k]=Wr2[k][n], WpsB/WpvB straight bf16 copies.
// ---------------------------------------------------------------------------
__global__ __launch_bounds__(256) void conv_w(
    const float* __restrict__ Ws1, const float* __restrict__ Ws2,
    const float* __restrict__ Wr1, const float* __restrict__ Wr2,
    const float* __restrict__ Wps, const float* __restrict__ Wpv,
    unsigned short* __restrict__ wb)
{
    int i = blockIdx.x * 256 + threadIdx.x;   // grid covers exactly W_TOTAL
    if (i < 24576) {
        int n = i / 192, k = i - n * 192;
        wb[O_WS1T + i] = f2bf(Ws1[k * 128 + n]);
    } else if (i < 65536) {
        int j = i - 24576; int n = j / 128, k = j - n * 128;
        wb[i] = f2bf(Ws2[k * 320 + n]);
    } else if (i < 69632) {
        int j = i - 65536; int n = j / 32, k = j - n * 32;
        wb[i] = (k < 20) ? f2bf(Wr1[k * 128 + n]) : (unsigned short)0;
    } else if (i < 110592) {
        int j = i - 69632; int n = j / 128, k = j - n * 128;
        wb[i] = f2bf(Wr2[k * 320 + n]);
    } else if (i < 118784) {
        wb[i] = f2bf(Wps[i - 110592]);
    } else {
        wb[i] = f2bf(Wpv[i - 118784]);
    }
}

// ---------------------------------------------------------------------------
// Kernel 1: node pre-projection + gate. 16 nodes/block; W_pre_s/W_pre_v staged
// once per block in LDS (kills the per-node 32KB weight re-fetch).
// ---------------------------------------------------------------------------
__global__ __launch_bounds__(256) void node_pre_kernel(
    const float* __restrict__ x,
    const float* __restrict__ W_pre_s, const float* __restrict__ b_pre_s,
    const float* __restrict__ W_pre_v,
    const float* __restrict__ gw_pre, const float* __restrict__ gb_pre,
    float* __restrict__ s_p, float* __restrict__ v_p)
{
    __shared__ float Ws[4096];
    __shared__ float Wv[4096];
    __shared__ float xsb[4][64];
    __shared__ float xvb[4][192];
    int tid = threadIdx.x;
#pragma unroll
    for (int i = 0; i < 4; i++) {
        int idx = i * 256 + tid;
        ((float4*)Ws)[idx] = ((const float4*)W_pre_s)[idx];
        ((float4*)Wv)[idx] = ((const float4*)W_pre_v)[idx];
    }
    __syncthreads();
    int w = tid >> 6, t = tid & 63;
    float bsv = b_pre_s[t], gwv = gw_pre[t], gbv = gb_pre[t];
    for (int it = 0; it < 4; it++) {
        int n = blockIdx.x * 16 + it * 4 + w;
        {
            float4 v = ((const float4*)(x + n * 256))[t];
            int idx = t * 4;
            float tmp[4] = {v.x, v.y, v.z, v.w};
#pragma unroll
            for (int i2 = 0; i2 < 4; i2++) {
                int id = idx + i2;
                if (id < 64) xsb[w][id] = tmp[i2];
                else         xvb[w][id - 64] = tmp[i2];
            }
        }
        __syncthreads();
        float acc_s = bsv;
        float a0 = 0.f, a1 = 0.f, a2 = 0.f;
        for (int uu = 0; uu < 64; uu++) {
            float xsu = xsb[w][uu];
            acc_s += xsu * Ws[uu * 64 + t];
            float wv = Wv[uu * 64 + t];
            a0 += xvb[w][uu * 3 + 0] * wv;
            a1 += xvb[w][uu * 3 + 1] * wv;
            a2 += xvb[w][uu * 3 + 2] * wv;
        }
        float nrm = sqrtf(a0 * a0 + a1 * a1 + a2 * a2 + 1e-12f);
        float g = silu_f(nrm * gwv + gbv);
        s_p[n * 64 + t] = silu_f(acc_s);
        float* vp = v_p + (n * 64 + t) * 3;
        vp[0] = a0 * g; vp[1] = a1 * g; vp[2] = a2 * g;
        __syncthreads();
    }
}

// ---------------------------------------------------------------------------
// Kernel 2: edge pipeline. 32 edges/block (4 waves). Big GEMMs via bf16 MFMA
// 16x16x32 (fp32 accumulate); TP/gate/post stages are the proven fp32 path.
// LDS (45056B, regions overlaid with barriers between lifetimes):
//   A: aS  [32][200] bf16  @0      (s0; later ea [32][32] overlay)
//   B: hB  [32][136] bf16  @12800  (h1, then hr)
//   C: wC  [320][33] bf16  @21504  (tp_w transpose-routing; stride 33 = conflict-free)
//   D: 4 x 2816 f32        @0      (per-wave stage-6/7 buffers, after C is drained)
// ---------------------------------------------------------------------------
__global__ __launch_bounds__(256, 3) void edge_kernel(
    const float* __restrict__ x,
    const float* __restrict__ edge_attr,
    const float* __restrict__ fij_in,
    const float* __restrict__ bs1, const float* __restrict__ bs2,
    const float* __restrict__ br1, const float* __restrict__ br2,
    const float* __restrict__ gw_post, const float* __restrict__ gb_post,
    const int* __restrict__ ei,
    const float* __restrict__ s_p, const float* __restrict__ v_p,
    const unsigned short* __restrict__ wb,
    float* __restrict__ out)
{
    __shared__ __align__(16) unsigned char LB[45056];
    unsigned short* aS  = (unsigned short*)LB;             // [32][200]
    unsigned short* hB  = (unsigned short*)(LB + 12800);   // [32][136]
    unsigned short* wC  = (unsigned short*)(LB + 21504);   // [320][33]
    unsigned short* eaL = (unsigned short*)LB;             // [32][32] overlay

    int tid = threadIdx.x;
    int w  = tid >> 6;          // wave
    int u  = tid & 63;          // lane
    int lr = u & 15;            // row/col within 16-tile
    int lk = (u >> 4) << 3;     // k offset 0,8,16,24
    const f32x4 FZ = {0.f, 0.f, 0.f, 0.f};

    // ===== stage G: gather s0 = [xs_i | xs_j | dot_v] -> aS (bf16) =====
    {
        int e = tid >> 3, p = tid & 7;
        int eg = blockIdx.x * 32 + e;
        int sp = ei[eg], dp = ei[NE + eg];
        const float* xr = x + sp * 256;
        const float* yr = x + dp * 256;
        int c0 = p * 8;
        float4 xi0 = *(const float4*)(xr + c0);
        float4 xi1 = *(const float4*)(xr + c0 + 4);
        float4 xj0 = *(const float4*)(yr + c0);
        float4 xj1 = *(const float4*)(yr + c0 + 4);
        float vi[24], vj[24];
#pragma unroll
        for (int q = 0; q < 6; q++) {
            *(float4*)&vi[q * 4] = *(const float4*)(xr + 64 + 3 * c0 + q * 4);
            *(float4*)&vj[q * 4] = *(const float4*)(yr + 64 + 3 * c0 + q * 4);
        }
        bf16x8 t0, t1, t2;
        t0[0] = (short)f2bf(xi0.x); t0[1] = (short)f2bf(xi0.y);
        t0[2] = (short)f2bf(xi0.z); t0[3] = (short)f2bf(xi0.w);
        t0[4] = (short)f2bf(xi1.x); t0[5] = (short)f2bf(xi1.y);
        t0[6] = (short)f2bf(xi1.z); t0[7] = (short)f2bf(xi1.w);
        t1[0] = (short)f2bf(xj0.x); t1[1] = (short)f2bf(xj0.y);
        t1[2] = (short)f2bf(xj0.z); t1[3] = (short)f2bf(xj0.w);
        t1[4] = (short)f2bf(xj1.x); t1[5] = (short)f2bf(xj1.y);
        t1[6] = (short)f2bf(xj1.z); t1[7] = (short)f2bf(xj1.w);
#pragma unroll
        for (int j = 0; j < 8; j++)
            t2[j] = (short)f2bf(vi[3*j]*vj[3*j] + vi[3*j+1]*vj[3*j+1] + vi[3*j+2]*vj[3*j+2]);
        *(bf16x8*)(aS + e * 200 + c0)       = t0;
        *(bf16x8*)(aS + e * 200 + 64 + c0)  = t1;
        *(bf16x8*)(aS + e * 200 + 128 + c0) = t2;
    }
    __syncthreads();

    // ===== H1: h1 = silu(s0 @ Ws1 + bs1) ; M=32,N=128,K=192 =====
    int colA = (w << 5) + lr;    // wave w owns cols [32w, 32w+32)
    int colB = colA + 16;
    {
        f32x4 a00 = FZ, a01 = FZ, a10 = FZ, a11 = FZ;
        const unsigned short* B1 = wb + O_WS1T;
#pragma unroll
        for (int kk = 0; kk < 6; kk++) {
            int k0 = kk * 32 + lk;
            bf16x8 fa0 = *(const bf16x8*)(aS + lr * 200 + k0);
            bf16x8 fa1 = *(const bf16x8*)(aS + (16 + lr) * 200 + k0);
            bf16x8 fb0 = *(const bf16x8*)(B1 + colA * 192 + k0);
            bf16x8 fb1 = *(const bf16x8*)(B1 + colB * 192 + k0);
            a00 = __builtin_amdgcn_mfma_f32_16x16x32_bf16(fa0, fb0, a00, 0, 0, 0);
            a10 = __builtin_amdgcn_mfma_f32_16x16x32_bf16(fa1, fb0, a10, 0, 0, 0);
            a01 = __builtin_amdgcn_mfma_f32_16x16x32_bf16(fa0, fb1, a01, 0, 0, 0);
            a11 = __builtin_amdgcn_mfma_f32_16x16x32_bf16(fa1, fb1, a11, 0, 0, 0);
        }
        float biasA = bs1[colA], biasB = bs1[colB];
        int rowb = (u >> 4) << 2;
#pragma unroll
        for (int r = 0; r < 4; r++) {
            hB[(rowb + r) * 136 + colA]      = f2bf(silu_f(a00[r] + biasA));
            hB[(16 + rowb + r) * 136 + colA] = f2bf(silu_f(a10[r] + biasA));
            hB[(rowb + r) * 136 + colB]      = f2bf(silu_f(a01[r] + biasB));
            hB[(16 + rowb + r) * 136 + colB] = f2bf(silu_f(a11[r] + biasB));
        }
    }
    __syncthreads();

    // ===== ea gather (overlay A) + H2: tp_a = h1 @ Ws2 + bs2 (kept in regs) =====
    {
        int e = tid >> 3, p = tid & 7;
        int eg = blockIdx.x * 32 + e;
        bf16x4 t;
#pragma unroll
        for (int j = 0; j < 4; j++) {
            int c = p * 4 + j;
            t[j] = (c < 20) ? (short)f2bf(edge_attr[eg * 20 + c]) : (short)0;
        }
        *(bf16x4*)(eaL + e * 32 + p * 4) = t;
    }
    f32x4 tpa[2][5];
#pragma unroll
    for (int i = 0; i < 5; i++) { tpa[0][i] = FZ; tpa[1][i] = FZ; }
    {
        const unsigned short* B2 = wb + O_WS2T;
        int cb = 80 * w + lr;    // wave w owns cols [80w, 80w+80)
#pragma unroll
        for (int kk = 0; kk < 4; kk++) {
            int k0 = kk * 32 + lk;
            bf16x8 fa0 = *(const bf16x8*)(hB + lr * 136 + k0);
            bf16x8 fa1 = *(const bf16x8*)(hB + (16 + lr) * 136 + k0);
#pragma unroll
            for (int i = 0; i < 5; i++) {
                bf16x8 fb = *(const bf16x8*)(B2 + (cb + 16 * i) * 128 + k0);
                tpa[0][i] = __builtin_amdgcn_mfma_f32_16x16x32_bf16(fa0, fb, tpa[0][i], 0, 0, 0);
                tpa[1][i] = __builtin_amdgcn_mfma_f32_16x16x32_bf16(fa1, fb, tpa[1][i], 0, 0, 0);
            }
        }
    }
    __syncthreads();

    // ===== R1: hr = silu(ea @ Wr1 + br1) ; K=32 (padded) -> hB =====
    {
        f32x4 ra00 = FZ, ra01 = FZ, ra10 = FZ, ra11 = FZ;
        const unsigned short* BR = wb + O_WR1T;
        bf16x8 fa0 = *(const bf16x8*)(eaL + lr * 32 + lk);
        bf16x8 fa1 = *(const bf16x8*)(eaL + (16 + lr) * 32 + lk);
        bf16x8 fb0 = *(const bf16x8*)(BR + colA * 32 + lk);
        bf16x8 fb1 = *(const bf16x8*)(BR + colB * 32 + lk);
        ra00 = __builtin_amdgcn_mfma_f32_16x16x32_bf16(fa0, fb0, ra00, 0, 0, 0);
        ra10 = __builtin_amdgcn_mfma_f32_16x16x32_bf16(fa1, fb0, ra10, 0, 0, 0);
        ra01 = __builtin_amdgcn_mfma_f32_16x16x32_bf16(fa0, fb1, ra01, 0, 0, 0);
        ra11 = __builtin_amdgcn_mfma_f32_16x16x32_bf16(fa1, fb1, ra11, 0, 0, 0);
        float biasA = br1[colA], biasB = br1[colB];
        int rowb = (u >> 4) << 2;
#pragma unroll
        for (int r = 0; r < 4; r++) {
            hB[(rowb + r) * 136 + colA]      = f2bf(silu_f(ra00[r] + biasA));
            hB[(16 + rowb + r) * 136 + colA] = f2bf(silu_f(ra10[r] + biasA));
            hB[(rowb + r) * 136 + colB]      = f2bf(silu_f(ra01[r] + biasB));
            hB[(16 + rowb + r) * 136 + colB] = f2bf(silu_f(ra11[r] + biasB));
        }
    }
    __syncthreads();

    // ===== R2: tp_w = (hr @ Wr2 + br2) * tp_a -> wC [320][33] bf16 =====
    {
        f32x4 wr[2][5];
#pragma unroll
        for (int i = 0; i < 5; i++) { wr[0][i] = FZ; wr[1][i] = FZ; }
        const unsigned short* B3 = wb + O_WR2T;
        int cb = 80 * w + lr;
#pragma unroll
        for (int kk = 0; kk < 4; kk++) {
            int k0 = kk * 32 + lk;
            bf16x8 fa0 = *(const bf16x8*)(hB + lr * 136 + k0);
            bf16x8 fa1 = *(const bf16x8*)(hB + (16 + lr) * 136 + k0);
#pragma unroll
            for (int i = 0; i < 5; i++) {
                bf16x8 fb = *(const bf16x8*)(B3 + (cb + 16 * i) * 128 + k0);
                wr[0][i] = __builtin_amdgcn_mfma_f32_16x16x32_bf16(fa0, fb, wr[0][i], 0, 0, 0);
                wr[1][i] = __builtin_amdgcn_mfma_f32_16x16x32_bf16(fa1, fb, wr[1][i], 0, 0, 0);
            }
        }
        int rowb = (u >> 4) << 2;
#pragma unroll
        for (int i = 0; i < 5; i++) {
            int col = cb + 16 * i;
            float b2 = bs2[col], c2 = br2[col];
#pragma unroll
            for (int mt = 0; mt < 2; mt++)
#pragma unroll
                for (int r = 0; r < 4; r++) {
                    float tv = tpa[mt][i][r] + b2;
                    float rv = wr[mt][i][r] + c2;
                    wC[col * 33 + mt * 16 + rowb + r] = f2bf(tv * rv);
                }
        }
    }
    __syncthreads();

    // ===== drain wC -> per-lane wgt[5][8] (then C region is dead) =====
    float wgt[5][8];
    {
        int eb = w * 8;
#pragma unroll
        for (int m = 0; m < 5; m++)
#pragma unroll
            for (int e = 0; e < 8; e++)
                wgt[m][e] = bf2f(wC[(m * 64 + u) * 33 + eb + e]);
    }
    __syncthreads();

    // ===== stage 6/7: tensor product + post gate + post GEMMs (fp32 path) =====
    float* SD   = ((float*)LB) + w * 2816;   // D overlay, per-wave
    float* osbT = SD;            // [128][4]
    float* ovT  = SD + 512;      // [192][12]
    float* obB  = SD;            // [4][256]
    int e8 = blockIdx.x * 32 + w * 8;
    const unsigned short* wps = wb + O_WPS;
    const unsigned short* wpv = wb + O_WPV;

#pragma unroll
    for (int p = 0; p < 2; p++) {
#pragma unroll
        for (int e = 0; e < 4; e++) {
            int el = p * 4 + e;
            int eg = e8 + el;
            int sp = ei[eg], dp = ei[NE + eg];
            float si = s_p[sp * 64 + u];
            float sj = s_p[dp * 64 + u];
            const float* vip = v_p + (sp * 64 + u) * 3;
            const float* vjp = v_p + (dp * 64 + u) * 3;
            float vi0 = vip[0], vi1 = vip[1], vi2 = vip[2];
            float vj0 = vjp[0], vj1 = vjp[1], vj2 = vjp[2];
            float dv = vi0 * vj0 + vi1 * vj1 + vi2 * vj2;

            float w1v = wgt[0][el], w2v = wgt[1][el], w3v = wgt[2][el];
            float w4v = wgt[3][el], w5v = wgt[4][el];

            float os1 = silu_f(w1v * si * sj);
            float os2 = silu_f(w4v * dv * INV_SQRT3);

            float r00 = w2v * si * vj0, r01 = w2v * si * vj1, r02 = w2v * si * vj2;
            float r10 = w3v * sj * vi0, r11 = w3v * sj * vi1, r12 = w3v * sj * vi2;
            float cx = vi1 * vj2 - vi2 * vj1;
            float cy = vi2 * vj0 - vi0 * vj2;
            float cz = vi0 * vj1 - vi1 * vj0;
            float r20 = w5v * cx * INV_SQRT2;
            float r21 = w5v * cy * INV_SQRT2;
            float r22 = w5v * cz * INV_SQRT2;

            float n0 = sqrtf(r00 * r00 + r01 * r01 + r02 * r02 + 1e-12f);
            float g0 = silu_f(n0 * gw_post[u] + gb_post[u]);
            float n1 = sqrtf(r10 * r10 + r11 * r11 + r12 * r12 + 1e-12f);
            float g1 = silu_f(n1 * gw_post[64 + u] + gb_post[64 + u]);
            float n2 = sqrtf(r20 * r20 + r21 * r21 + r22 * r22 + 1e-12f);
            float g2 = silu_f(n2 * gw_post[128 + u] + gb_post[128 + u]);

            osbT[u * 4 + e]        = os1;
            osbT[(64 + u) * 4 + e] = os2;
            ovT[u * 12 + 0 * 4 + e] = r00 * g0;
            ovT[u * 12 + 1 * 4 + e] = r01 * g0;
            ovT[u * 12 + 2 * 4 + e] = r02 * g0;
            ovT[(64 + u) * 12 + 0 * 4 + e] = r10 * g1;
            ovT[(64 + u) * 12 + 1 * 4 + e] = r11 * g1;
            ovT[(64 + u) * 12 + 2 * 4 + e] = r12 * g1;
            ovT[(128 + u) * 12 + 0 * 4 + e] = r20 * g2;
            ovT[(128 + u) * 12 + 1 * 4 + e] = r21 * g2;
            ovT[(128 + u) * 12 + 2 * 4 + e] = r22 * g2;
        }
        __syncthreads();

        float fs[4] = {0.f, 0.f, 0.f, 0.f};
#pragma unroll 2
        for (int k = 0; k < 128; k++) {
            float4 ov = *(const float4*)&osbT[k * 4];
            float wv = bf2f(wps[k * 64 + u]);
            fs[0] += ov.x * wv; fs[1] += ov.y * wv;
            fs[2] += ov.z * wv; fs[3] += ov.w * wv;
        }
        float fv[4][3];
#pragma unroll
        for (int e = 0; e < 4; e++) { fv[e][0] = 0.f; fv[e][1] = 0.f; fv[e][2] = 0.f; }
#pragma unroll 2
        for (int k = 0; k < 192; k++) {
            float4 q0 = *(const float4*)&ovT[k * 12];
            float4 q1 = *(const float4*)&ovT[k * 12 + 4];
            float4 q2 = *(const float4*)&ovT[k * 12 + 8];
            float wv = bf2f(wpv[k * 64 + u]);
            fv[0][0] += q0.x * wv; fv[1][0] += q0.y * wv; fv[2][0] += q0.z * wv; fv[3][0] += q0.w * wv;
            fv[0][1] += q1.x * wv; fv[1][1] += q1.y * wv; fv[2][1] += q1.z * wv; fv[3][1] += q1.w * wv;
            fv[0][2] += q2.x * wv; fv[1][2] += q2.y * wv; fv[2][2] += q2.z * wv; fv[3][2] += q2.w * wv;
        }
        __syncthreads();

#pragma unroll
        for (int e = 0; e < 4; e++) {
            obB[e * 256 + u] = fs[e];
            obB[e * 256 + 64 + 3 * u + 0] = fv[e][0];
            obB[e * 256 + 64 + 3 * u + 1] = fv[e][1];
            obB[e * 256 + 64 + 3 * u + 2] = fv[e][2];
        }
        __syncthreads();

#pragma unroll
        for (int e = 0; e < 4; e++) {
            int eg = e8 + p * 4 + e;
            float4 fin = ((const float4*)fij_in)[eg * 64 + u];
            float4 o4 = *(const float4*)&obB[e * 256 + 4 * u];
            o4.x += fin.x; o4.y += fin.y; o4.z += fin.z; o4.w += fin.w;
            ((float4*)out)[eg * 64 + u] = o4;
        }
        __syncthreads();
    }
}

extern "C" void kernel_launch(void* const* d_in, const int* in_sizes, int n_in,
                              void* d_out, int out_size, void* d_ws, size_t ws_size,
                              hipStream_t stream)
{
    const float* x         = (const float*)d_in[0];
    const float* edge_attr = (const float*)d_in[1];
    const float* fij_in    = (const float*)d_in[2];
    const float* W_pre_s   = (const float*)d_in[3];
    const float* b_pre_s   = (const float*)d_in[4];
    const float* W_pre_v   = (const float*)d_in[5];
    const float* gw_pre    = (const float*)d_in[6];
    const float* gb_pre    = (const float*)d_in[7];
    const float* Ws1       = (const float*)d_in[8];
    const float* bs1       = (const float*)d_in[9];
    const float* Ws2       = (const float*)d_in[10];
    const float* bs2       = (const float*)d_in[11];
    const float* Wr1       = (const float*)d_in[12];
    const float* br1       = (const float*)d_in[13];
    const float* Wr2       = (const float*)d_in[14];
    const float* br2       = (const float*)d_in[15];
    const float* gw_post   = (const float*)d_in[16];
    const float* gb_post   = (const float*)d_in[17];
    const float* W_post_s  = (const float*)d_in[18];
    const float* W_post_v  = (const float*)d_in[19];
    const int*   ei        = (const int*)d_in[20];
    float* out = (float*)d_out;

    // workspace: s_p (N*64 f32) + v_p (N*192 f32) = 10.24 MB, then 256 KB bf16 weights
    float* s_p = (float*)d_ws;
    float* v_p = s_p + NN * 64;
    unsigned short* wb = (unsigned short*)(v_p + NN * 192);

    conv_w<<<W_TOTAL / 256, 256, 0, stream>>>(Ws1, Ws2, Wr1, Wr2, W_post_s, W_post_v, wb);
    node_pre_kernel<<<NN / 16, 256, 0, stream>>>(x, W_pre_s, b_pre_s, W_pre_v,
                                                 gw_pre, gb_pre, s_p, v_p);
    edge_kernel<<<NE / 32, 256, 0, stream>>>(x, edge_attr, fij_in,
                                             bs1, bs2, br1, br2,
                                             gw_post, gb_post,
                                             ei, s_p, v_p, wb, out);
}

// Round 4
// 528.637 us; speedup vs baseline: 4.8691x; 1.8369x over previous
//
#include <hip/hip_runtime.h>

#define NN 10000
#define NE 160000
#define INV_SQRT3 0.57735026918962576f
#define INV_SQRT2 0.70710678118654752f

// bf16 weight workspace offsets (in ushorts)
#define O_WS1T 0        // [128][192]
#define O_WS2T 24576    // [320][128]
#define O_WR1T 65536    // [128][32]  (K padded 20->32 with zeros)
#define O_WR2T 69632    // [320][128]
#define O_WPST 110592   // [64][128]  W_post_s transposed: [n][k]
#define O_WPVT 118784   // [64][192]  W_post_v transposed: [n][k]
#define W_TOTAL 131072

typedef __attribute__((ext_vector_type(8))) short bf16x8;
typedef __attribute__((ext_vector_type(4))) short bf16x4;
typedef __attribute__((ext_vector_type(4))) float f32x4;

__device__ __forceinline__ float silu_f(float x) { return x / (1.0f + __expf(-x)); }
__device__ __forceinline__ unsigned short f2bf(float f) {
    unsigned int uu = __float_as_uint(f);
    uu += 0x7fffu + ((uu >> 16) & 1u);     // RNE
    return (unsigned short)(uu >> 16);
}
__device__ __forceinline__ float bf2f(unsigned short v) {
    return __uint_as_float(((unsigned int)v) << 16);
}

// ---------------------------------------------------------------------------
// Kernel 0: one-time weight convert/transpose to bf16.
// ---------------------------------------------------------------------------
__global__ __launch_bounds__(256) void conv_w(
    const float* __restrict__ Ws1, const float* __restrict__ Ws2,
    const float* __restrict__ Wr1, const float* __restrict__ Wr2,
    const float* __restrict__ Wps, const float* __restrict__ Wpv,
    unsigned short* __restrict__ wb)
{
    int i = blockIdx.x * 256 + threadIdx.x;   // grid covers exactly W_TOTAL
    if (i < 24576) {
        int n = i / 192, k = i - n * 192;
        wb[O_WS1T + i] = f2bf(Ws1[k * 128 + n]);
    } else if (i < 65536) {
        int j = i - 24576; int n = j / 128, k = j - n * 128;
        wb[i] = f2bf(Ws2[k * 320 + n]);
    } else if (i < 69632) {
        int j = i - 65536; int n = j / 32, k = j - n * 32;
        wb[i] = (k < 20) ? f2bf(Wr1[k * 128 + n]) : (unsigned short)0;
    } else if (i < 110592) {
        int j = i - 69632; int n = j / 128, k = j - n * 128;
        wb[i] = f2bf(Wr2[k * 320 + n]);
    } else if (i < 118784) {
        int j = i - 110592; int n = j >> 7, k = j & 127;
        wb[i] = f2bf(Wps[k * 64 + n]);
    } else {
        int j = i - 118784; int n = j / 192, k = j - n * 192;
        wb[i] = f2bf(Wpv[k * 64 + n]);
    }
}

// ---------------------------------------------------------------------------
// Kernel 1: node pre-projection + gate. 16 nodes/block; weights staged in LDS.
// ---------------------------------------------------------------------------
__global__ __launch_bounds__(256) void node_pre_kernel(
    const float* __restrict__ x,
    const float* __restrict__ W_pre_s, const float* __restrict__ b_pre_s,
    const float* __restrict__ W_pre_v,
    const float* __restrict__ gw_pre, const float* __restrict__ gb_pre,
    float* __restrict__ s_p, float* __restrict__ v_p)
{
    __shared__ float Ws[4096];
    __shared__ float Wv[4096];
    __shared__ float xsb[4][64];
    __shared__ float xvb[4][192];
    int tid = threadIdx.x;
#pragma unroll
    for (int i = 0; i < 4; i++) {
        int idx = i * 256 + tid;
        ((float4*)Ws)[idx] = ((const float4*)W_pre_s)[idx];
        ((float4*)Wv)[idx] = ((const float4*)W_pre_v)[idx];
    }
    __syncthreads();
    int w = tid >> 6, t = tid & 63;
    float bsv = b_pre_s[t], gwv = gw_pre[t], gbv = gb_pre[t];
    for (int it = 0; it < 4; it++) {
        int n = blockIdx.x * 16 + it * 4 + w;
        {
            float4 v = ((const float4*)(x + n * 256))[t];
            int idx = t * 4;
            float tmp[4] = {v.x, v.y, v.z, v.w};
#pragma unroll
            for (int i2 = 0; i2 < 4; i2++) {
                int id = idx + i2;
                if (id < 64) xsb[w][id] = tmp[i2];
                else         xvb[w][id - 64] = tmp[i2];
            }
        }
        __syncthreads();
        float acc_s = bsv;
        float a0 = 0.f, a1 = 0.f, a2 = 0.f;
        for (int uu = 0; uu < 64; uu++) {
            float xsu = xsb[w][uu];
            acc_s += xsu * Ws[uu * 64 + t];
            float wv = Wv[uu * 64 + t];
            a0 += xvb[w][uu * 3 + 0] * wv;
            a1 += xvb[w][uu * 3 + 1] * wv;
            a2 += xvb[w][uu * 3 + 2] * wv;
        }
        float nrm = sqrtf(a0 * a0 + a1 * a1 + a2 * a2 + 1e-12f);
        float g = silu_f(nrm * gwv + gbv);
        s_p[n * 64 + t] = silu_f(acc_s);
        float* vp = v_p + (n * 64 + t) * 3;
        vp[0] = a0 * g; vp[1] = a1 * g; vp[2] = a2 * g;
        __syncthreads();
    }
}

// ---------------------------------------------------------------------------
// Kernel 2: edge pipeline, fully MFMA'd. 32 edges/block (4 waves).
// LDS 45056B (+ 256B edge-index cache), regions overlaid across stages:
//   A: aS  [32][200] bf16 @0      (s0; eaL [32][32] overlay)
//   B: hB  [32][136] bf16 @12800  (h1, then hr)
//   C: wC  [320][33] bf16 @21504  (tp_w transpose-routing)
//   post: pAs [32][128] bf16 @0, pAv 3x[32][192] bf16 @8192  (XOR-swizzled)
//   post: ob  [32][260] f32 @0    (output staging, after pA consumed)
// ---------------------------------------------------------------------------
__global__ __launch_bounds__(256, 3) void edge_kernel(
    const float* __restrict__ x,
    const float* __restrict__ edge_attr,
    const float* __restrict__ fij_in,
    const float* __restrict__ bs1, const float* __restrict__ bs2,
    const float* __restrict__ br1, const float* __restrict__ br2,
    const float* __restrict__ gw_post, const float* __restrict__ gb_post,
    const int* __restrict__ ei,
    const float* __restrict__ s_p, const float* __restrict__ v_p,
    const unsigned short* __restrict__ wb,
    float* __restrict__ out)
{
    __shared__ __align__(16) unsigned char LB[45056];
    __shared__ int eis[32], eid[32];
    unsigned short* aS  = (unsigned short*)LB;             // [32][200]
    unsigned short* hB  = (unsigned short*)(LB + 12800);   // [32][136]
    unsigned short* wC  = (unsigned short*)(LB + 21504);   // [320][33]
    unsigned short* eaL = (unsigned short*)LB;             // [32][32] overlay
    unsigned short* pAs = (unsigned short*)LB;             // [32][128] overlay
    unsigned short* pAv = (unsigned short*)(LB + 8192);    // 3 x [32][192] overlay
    float*          ob  = (float*)LB;                      // [32][260] overlay

    int tid = threadIdx.x;
    int w  = tid >> 6;          // wave
    int u  = tid & 63;          // lane
    int lr = u & 15;            // row/col within 16-tile
    int lk = (u >> 4) << 3;     // k offset 0,8,16,24
    const f32x4 FZ = {0.f, 0.f, 0.f, 0.f};

    // ===== stage G: gather s0 = [xs_i | xs_j | dot_v] -> aS (bf16) =====
    {
        int e = tid >> 3, p = tid & 7;
        int eg = blockIdx.x * 32 + e;
        int sp = ei[eg], dp = ei[NE + eg];
        if (p == 0) { eis[e] = sp; eid[e] = dp; }
        const float* xr = x + sp * 256;
        const float* yr = x + dp * 256;
        int c0 = p * 8;
        float4 xi0 = *(const float4*)(xr + c0);
        float4 xi1 = *(const float4*)(xr + c0 + 4);
        float4 xj0 = *(const float4*)(yr + c0);
        float4 xj1 = *(const float4*)(yr + c0 + 4);
        float vi[24], vj[24];
#pragma unroll
        for (int q = 0; q < 6; q++) {
            *(float4*)&vi[q * 4] = *(const float4*)(xr + 64 + 3 * c0 + q * 4);
            *(float4*)&vj[q * 4] = *(const float4*)(yr + 64 + 3 * c0 + q * 4);
        }
        bf16x8 t0, t1, t2;
        t0[0] = (short)f2bf(xi0.x); t0[1] = (short)f2bf(xi0.y);
        t0[2] = (short)f2bf(xi0.z); t0[3] = (short)f2bf(xi0.w);
        t0[4] = (short)f2bf(xi1.x); t0[5] = (short)f2bf(xi1.y);
        t0[6] = (short)f2bf(xi1.z); t0[7] = (short)f2bf(xi1.w);
        t1[0] = (short)f2bf(xj0.x); t1[1] = (short)f2bf(xj0.y);
        t1[2] = (short)f2bf(xj0.z); t1[3] = (short)f2bf(xj0.w);
        t1[4] = (short)f2bf(xj1.x); t1[5] = (short)f2bf(xj1.y);
        t1[6] = (short)f2bf(xj1.z); t1[7] = (short)f2bf(xj1.w);
#pragma unroll
        for (int j = 0; j < 8; j++)
            t2[j] = (short)f2bf(vi[3*j]*vj[3*j] + vi[3*j+1]*vj[3*j+1] + vi[3*j+2]*vj[3*j+2]);
        *(bf16x8*)(aS + e * 200 + c0)       = t0;
        *(bf16x8*)(aS + e * 200 + 64 + c0)  = t1;
        *(bf16x8*)(aS + e * 200 + 128 + c0) = t2;
    }
    __syncthreads();

    // ===== H1: h1 = silu(s0 @ Ws1 + bs1) ; M=32,N=128,K=192 =====
    int colA = (w << 5) + lr;    // wave w owns cols [32w, 32w+32)
    int colB = colA + 16;
    {
        f32x4 a00 = FZ, a01 = FZ, a10 = FZ, a11 = FZ;
        const unsigned short* B1 = wb + O_WS1T;
#pragma unroll
        for (int kk = 0; kk < 6; kk++) {
            int k0 = kk * 32 + lk;
            bf16x8 fa0 = *(const bf16x8*)(aS + lr * 200 + k0);
            bf16x8 fa1 = *(const bf16x8*)(aS + (16 + lr) * 200 + k0);
            bf16x8 fb0 = *(const bf16x8*)(B1 + colA * 192 + k0);
            bf16x8 fb1 = *(const bf16x8*)(B1 + colB * 192 + k0);
            a00 = __builtin_amdgcn_mfma_f32_16x16x32_bf16(fa0, fb0, a00, 0, 0, 0);
            a10 = __builtin_amdgcn_mfma_f32_16x16x32_bf16(fa1, fb0, a10, 0, 0, 0);
            a01 = __builtin_amdgcn_mfma_f32_16x16x32_bf16(fa0, fb1, a01, 0, 0, 0);
            a11 = __builtin_amdgcn_mfma_f32_16x16x32_bf16(fa1, fb1, a11, 0, 0, 0);
        }
        float biasA = bs1[colA], biasB = bs1[colB];
        int rowb = (u >> 4) << 2;
#pragma unroll
        for (int r = 0; r < 4; r++) {
            hB[(rowb + r) * 136 + colA]      = f2bf(silu_f(a00[r] + biasA));
            hB[(16 + rowb + r) * 136 + colA] = f2bf(silu_f(a10[r] + biasA));
            hB[(rowb + r) * 136 + colB]      = f2bf(silu_f(a01[r] + biasB));
            hB[(16 + rowb + r) * 136 + colB] = f2bf(silu_f(a11[r] + biasB));
        }
    }
    __syncthreads();

    // ===== ea gather (overlay A) + H2: tp_a = h1 @ Ws2 + bs2 (kept in regs) =====
    {
        int e = tid >> 3, p = tid & 7;
        int eg = blockIdx.x * 32 + e;
        bf16x4 t;
#pragma unroll
        for (int j = 0; j < 4; j++) {
            int c = p * 4 + j;
            t[j] = (c < 20) ? (short)f2bf(edge_attr[eg * 20 + c]) : (short)0;
        }
        *(bf16x4*)(eaL + e * 32 + p * 4) = t;
    }
    f32x4 tpa[2][5];
#pragma unroll
    for (int i = 0; i < 5; i++) { tpa[0][i] = FZ; tpa[1][i] = FZ; }
    {
        const unsigned short* B2 = wb + O_WS2T;
        int cb = 80 * w + lr;    // wave w owns cols [80w, 80w+80)
#pragma unroll
        for (int kk = 0; kk < 4; kk++) {
            int k0 = kk * 32 + lk;
            bf16x8 fa0 = *(const bf16x8*)(hB + lr * 136 + k0);
            bf16x8 fa1 = *(const bf16x8*)(hB + (16 + lr) * 136 + k0);
#pragma unroll
            for (int i = 0; i < 5; i++) {
                bf16x8 fb = *(const bf16x8*)(B2 + (cb + 16 * i) * 128 + k0);
                tpa[0][i] = __builtin_amdgcn_mfma_f32_16x16x32_bf16(fa0, fb, tpa[0][i], 0, 0, 0);
                tpa[1][i] = __builtin_amdgcn_mfma_f32_16x16x32_bf16(fa1, fb, tpa[1][i], 0, 0, 0);
            }
        }
    }
    __syncthreads();

    // ===== R1: hr = silu(ea @ Wr1 + br1) ; K=32 (padded) -> hB =====
    {
        f32x4 ra00 = FZ, ra01 = FZ, ra10 = FZ, ra11 = FZ;
        const unsigned short* BR = wb + O_WR1T;
        bf16x8 fa0 = *(const bf16x8*)(eaL + lr * 32 + lk);
        bf16x8 fa1 = *(const bf16x8*)(eaL + (16 + lr) * 32 + lk);
        bf16x8 fb0 = *(const bf16x8*)(BR + colA * 32 + lk);
        bf16x8 fb1 = *(const bf16x8*)(BR + colB * 32 + lk);
        ra00 = __builtin_amdgcn_mfma_f32_16x16x32_bf16(fa0, fb0, ra00, 0, 0, 0);
        ra10 = __builtin_amdgcn_mfma_f32_16x16x32_bf16(fa1, fb0, ra10, 0, 0, 0);
        ra01 = __builtin_amdgcn_mfma_f32_16x16x32_bf16(fa0, fb1, ra01, 0, 0, 0);
        ra11 = __builtin_amdgcn_mfma_f32_16x16x32_bf16(fa1, fb1, ra11, 0, 0, 0);
        float biasA = br1[colA], biasB = br1[colB];
        int rowb = (u >> 4) << 2;
#pragma unroll
        for (int r = 0; r < 4; r++) {
            hB[(rowb + r) * 136 + colA]      = f2bf(silu_f(ra00[r] + biasA));
            hB[(16 + rowb + r) * 136 + colA] = f2bf(silu_f(ra10[r] + biasA));
            hB[(rowb + r) * 136 + colB]      = f2bf(silu_f(ra01[r] + biasB));
            hB[(16 + rowb + r) * 136 + colB] = f2bf(silu_f(ra11[r] + biasB));
        }
    }
    __syncthreads();

    // ===== R2: tp_w = (hr @ Wr2 + br2) * tp_a -> wC [320][33] bf16 =====
    {
        f32x4 wr[2][5];
#pragma unroll
        for (int i = 0; i < 5; i++) { wr[0][i] = FZ; wr[1][i] = FZ; }
        const unsigned short* B3 = wb + O_WR2T;
        int cb = 80 * w + lr;
#pragma unroll
        for (int kk = 0; kk < 4; kk++) {
            int k0 = kk * 32 + lk;
            bf16x8 fa0 = *(const bf16x8*)(hB + lr * 136 + k0);
            bf16x8 fa1 = *(const bf16x8*)(hB + (16 + lr) * 136 + k0);
#pragma unroll
            for (int i = 0; i < 5; i++) {
                bf16x8 fb = *(const bf16x8*)(B3 + (cb + 16 * i) * 128 + k0);
                wr[0][i] = __builtin_amdgcn_mfma_f32_16x16x32_bf16(fa0, fb, wr[0][i], 0, 0, 0);
                wr[1][i] = __builtin_amdgcn_mfma_f32_16x16x32_bf16(fa1, fb, wr[1][i], 0, 0, 0);
            }
        }
        int rowb = (u >> 4) << 2;
#pragma unroll
        for (int i = 0; i < 5; i++) {
            int col = cb + 16 * i;
            float b2 = bs2[col], c2 = br2[col];
#pragma unroll
            for (int mt = 0; mt < 2; mt++)
#pragma unroll
                for (int r = 0; r < 4; r++) {
                    float tv = tpa[mt][i][r] + b2;
                    float rv = wr[mt][i][r] + c2;
                    wC[col * 33 + mt * 16 + rowb + r] = f2bf(tv * rv);
                }
        }
    }
    __syncthreads();

    // ===== drain wC -> per-lane wgt[5][8] =====
    float wgt[5][8];
    {
        int eb = w * 8;
#pragma unroll
        for (int m = 0; m < 5; m++)
#pragma unroll
            for (int e = 0; e < 8; e++)
                wgt[m][e] = bf2f(wC[(m * 64 + u) * 33 + eb + e]);
    }
    __syncthreads();   // before TP clobbers wC/aS/hB with pAs/pAv

    // ===== TP + post-gate -> pAs/pAv (bf16 [e][k], 16B-granule XOR swizzle) =====
    {
        float gwa = gw_post[u],       gba = gb_post[u];
        float gwb = gw_post[64 + u],  gbb = gb_post[64 + u];
        float gwc = gw_post[128 + u], gbc = gb_post[128 + u];
#pragma unroll
        for (int el = 0; el < 8; el++) {
            int er = w * 8 + el;
            int sp = eis[er], dp = eid[er];
            float si = s_p[sp * 64 + u];
            float sj = s_p[dp * 64 + u];
            const float* vip = v_p + (sp * 64 + u) * 3;
            const float* vjp = v_p + (dp * 64 + u) * 3;
            float vi0 = vip[0], vi1 = vip[1], vi2 = vip[2];
            float vj0 = vjp[0], vj1 = vjp[1], vj2 = vjp[2];
            float dv = vi0 * vj0 + vi1 * vj1 + vi2 * vj2;

            float w1v = wgt[0][el], w2v = wgt[1][el], w3v = wgt[2][el];
            float w4v = wgt[3][el], w5v = wgt[4][el];

            float os1 = silu_f(w1v * si * sj);
            float os2 = silu_f(w4v * dv * INV_SQRT3);

            float r00 = w2v * si * vj0, r01 = w2v * si * vj1, r02 = w2v * si * vj2;
            float r10 = w3v * sj * vi0, r11 = w3v * sj * vi1, r12 = w3v * sj * vi2;
            float cx = vi1 * vj2 - vi2 * vj1;
            float cy = vi2 * vj0 - vi0 * vj2;
            float cz = vi0 * vj1 - vi1 * vj0;
            float r20 = w5v * cx * INV_SQRT2;
            float r21 = w5v * cy * INV_SQRT2;
            float r22 = w5v * cz * INV_SQRT2;

            float n0 = sqrtf(r00 * r00 + r01 * r01 + r02 * r02 + 1e-12f);
            float g0 = silu_f(n0 * gwa + gba);
            float n1 = sqrtf(r10 * r10 + r11 * r11 + r12 * r12 + 1e-12f);
            float g1 = silu_f(n1 * gwb + gbb);
            float n2 = sqrtf(r20 * r20 + r21 * r21 + r22 * r22 + 1e-12f);
            float g2 = silu_f(n2 * gwc + gbc);

            int sw = (er & 7) << 3;          // swizzle: k ^= sw (16B granules)
            unsigned short* as_r = pAs + er * 128;
            as_r[u ^ sw]        = f2bf(os1);
            as_r[(64 + u) ^ sw] = f2bf(os2);
            unsigned short* av0 = pAv + er * 192;
            unsigned short* av1 = av0 + 6144;
            unsigned short* av2 = av1 + 6144;
            av0[u ^ sw]         = f2bf(r00 * g0);
            av0[(64 + u) ^ sw]  = f2bf(r10 * g1);
            av0[(128 + u) ^ sw] = f2bf(r20 * g2);
            av1[u ^ sw]         = f2bf(r01 * g0);
            av1[(64 + u) ^ sw]  = f2bf(r11 * g1);
            av1[(128 + u) ^ sw] = f2bf(r21 * g2);
            av2[u ^ sw]         = f2bf(r02 * g0);
            av2[(64 + u) ^ sw]  = f2bf(r12 * g1);
            av2[(128 + u) ^ sw] = f2bf(r22 * g2);
        }
    }
    __syncthreads();

    // ===== post GEMMs via MFMA: wave w owns output cols [16w,16w+16) =====
    f32x4 cs[2];
    f32x4 cv[3][2];
    cs[0] = FZ; cs[1] = FZ;
#pragma unroll
    for (int c = 0; c < 3; c++) { cv[c][0] = FZ; cv[c][1] = FZ; }
    {
        int swz = (lr & 7) << 3;   // (er&7) identical for er=lr and er=16+lr
        const unsigned short* Bs = wb + O_WPST + (16 * w + lr) * 128;
#pragma unroll
        for (int kk = 0; kk < 4; kk++) {
            int k0 = kk * 32 + lk;
            bf16x8 fb  = *(const bf16x8*)(Bs + k0);
            bf16x8 fa0 = *(const bf16x8*)(pAs + lr * 128 + (k0 ^ swz));
            bf16x8 fa1 = *(const bf16x8*)(pAs + (16 + lr) * 128 + (k0 ^ swz));
            cs[0] = __builtin_amdgcn_mfma_f32_16x16x32_bf16(fa0, fb, cs[0], 0, 0, 0);
            cs[1] = __builtin_amdgcn_mfma_f32_16x16x32_bf16(fa1, fb, cs[1], 0, 0, 0);
        }
        const unsigned short* Bv = wb + O_WPVT + (16 * w + lr) * 192;
#pragma unroll
        for (int kk = 0; kk < 6; kk++) {
            int k0 = kk * 32 + lk;
            bf16x8 fb = *(const bf16x8*)(Bv + k0);
            int ks = k0 ^ swz;
#pragma unroll
            for (int c = 0; c < 3; c++) {
                bf16x8 fa0 = *(const bf16x8*)(pAv + c * 6144 + lr * 192 + ks);
                bf16x8 fa1 = *(const bf16x8*)(pAv + c * 6144 + (16 + lr) * 192 + ks);
                cv[c][0] = __builtin_amdgcn_mfma_f32_16x16x32_bf16(fa0, fb, cv[c][0], 0, 0, 0);
                cv[c][1] = __builtin_amdgcn_mfma_f32_16x16x32_bf16(fa1, fb, cv[c][1], 0, 0, 0);
            }
        }
    }
    __syncthreads();   // pA consumed; ob overlays

    // ===== scatter accumulators -> ob [32][260] f32 =====
    {
        int rowb = (u >> 4) << 2;
        int cu = 16 * w + lr;
#pragma unroll
        for (int mt = 0; mt < 2; mt++) {
#pragma unroll
            for (int r = 0; r < 4; r++) {
                int er = mt * 16 + rowb + r;
                float* obr = ob + er * 260;
                obr[cu]              = cs[mt][r];
                obr[64 + 3 * cu + 0] = cv[0][mt][r];
                obr[64 + 3 * cu + 1] = cv[1][mt][r];
                obr[64 + 3 * cu + 2] = cv[2][mt][r];
            }
        }
    }
    __syncthreads();

    // ===== coalesced output + residual =====
#pragma unroll
    for (int el = 0; el < 8; el++) {
        int er = w * 8 + el;
        int eg = blockIdx.x * 32 + er;
        float4 fin = ((const float4*)fij_in)[eg * 64 + u];
        float4 o4 = *(const float4*)(ob + er * 260 + 4 * u);
        o4.x += fin.x; o4.y += fin.y; o4.z += fin.z; o4.w += fin.w;
        ((float4*)out)[eg * 64 + u] = o4;
    }
}

extern "C" void kernel_launch(void* const* d_in, const int* in_sizes, int n_in,
                              void* d_out, int out_size, void* d_ws, size_t ws_size,
                              hipStream_t stream)
{
    const float* x         = (const float*)d_in[0];
    const float* edge_attr = (const float*)d_in[1];
    const float* fij_in    = (const float*)d_in[2];
    const float* W_pre_s   = (const float*)d_in[3];
    const float* b_pre_s   = (const float*)d_in[4];
    const float* W_pre_v   = (const float*)d_in[5];
    const float* gw_pre    = (const float*)d_in[6];
    const float* gb_pre    = (const float*)d_in[7];
    const float* Ws1       = (const float*)d_in[8];
    const float* bs1       = (const float*)d_in[9];
    const float* Ws2       = (const float*)d_in[10];
    const float* bs2       = (const float*)d_in[11];
    const float* Wr1       = (const float*)d_in[12];
    const float* br1       = (const float*)d_in[13];
    const float* Wr2       = (const float*)d_in[14];
    const float* br2       = (const float*)d_in[15];
    const float* gw_post   = (const float*)d_in[16];
    const float* gb_post   = (const float*)d_in[17];
    const float* W_post_s  = (const float*)d_in[18];
    const float* W_post_v  = (const float*)d_in[19];
    const int*   ei        = (const int*)d_in[20];
    float* out = (float*)d_out;

    // workspace: s_p (N*64 f32) + v_p (N*192 f32) = 10.24 MB, then 256 KB bf16 weights
    float* s_p = (float*)d_ws;
    float* v_p = s_p + NN * 64;
    unsigned short* wb = (unsigned short*)(v_p + NN * 192);

    conv_w<<<W_TOTAL / 256, 256, 0, stream>>>(Ws1, Ws2, Wr1, Wr2, W_post_s, W_post_v, wb);
    node_pre_kernel<<<NN / 16, 256, 0, stream>>>(x, W_pre_s, b_pre_s, W_pre_v,
                                                 gw_pre, gb_pre, s_p, v_p);
    edge_kernel<<<NE / 32, 256, 0, stream>>>(x, edge_attr, fij_in,
                                             bs1, bs2, br1, br2,
                                             gw_post, gb_post,
                                             ei, s_p, v_p, wb, out);
}